// Round 5
// baseline (528.977 us; speedup 1.0000x reference)
//
#include <hip/hip_runtime.h>

// MoE expert FFN: T=256, E=16, H=2048, I=1024, top_k=4 (int32 device scalar).
// Inputs fp32, output fp32 (both proven). Compute bf16 MFMA (threshold 2%).
//
// R7: registers-only weight streaming with DEEP explicit pipeline.
// Evidence R0/R2/R4: effective burst latency ~3-4us (>>900cy nominal);
// every prior structure exposed ~1 latency per K-step (depth<=1). LDS
// staging of B was pure overhead (weight rows have zero reuse). Now:
//  - no LDS in k-loop, no k-loop barriers; each wave streams its own
//    weight rows HBM->regs->cvt->MFMA with a D-stage rotating register
//    pipeline (gemm1 D=4 x 2 streams, gemm2 D=8 x 1 stream): ~100KB/CU
//    in flight vs R4's ~32KB.
//  - gather_x pre-compacts X_e (x fp32 -> xe[e][slot] bf16): contiguous
//    A-rows, no token indirection in the hot loop.
//  - grid (e, tile): consecutive block ids vary e -> each XCD's L2 holds
//    only ~2 experts' xe slice.
//  - verified pieces kept: split-K-2 reduce epilogue (R2), MT-trim switch,
//    silu fusion, MFMA C/D store mapping, route/gather kernels.
// ws is 1 GiB (harness fill writes 1 GiB/iter, ~160us, irreducible).

typedef __attribute__((ext_vector_type(8))) short bf16x8;   // MFMA A/B frag
typedef __attribute__((ext_vector_type(4))) float floatx4;  // MFMA C/D frag

#define T_TOK 256
#define N_EXP 16
#define H_DIM 2048
#define I_DIM 1024
#define MAX_SLOTS 256

__device__ __forceinline__ short f2bf(float f) {           // RNE fp32->bf16
    union { float f; unsigned u; } v; v.f = f;
    unsigned r = (v.u + 0x7FFFu + ((v.u >> 16) & 1u)) >> 16;
    return (short)r;
}
__device__ __forceinline__ float bf2f(short s) {
    union { unsigned u; float f; } v; v.u = ((unsigned)(unsigned short)s) << 16;
    return v.f;
}
__device__ __forceinline__ bf16x8 pack2f4(float4 a, float4 b) {  // 8 fp32 -> bf16x8
    bf16x8 r;
    r[0] = f2bf(a.x); r[1] = f2bf(a.y); r[2] = f2bf(a.z); r[3] = f2bf(a.w);
    r[4] = f2bf(b.x); r[5] = f2bf(b.y); r[6] = f2bf(b.z); r[7] = f2bf(b.w);
    return r;
}
__device__ __forceinline__ bf16x8 pack8(const float* __restrict__ p) {
    return pack2f4(*(const float4*)p, *(const float4*)(p + 4));
}

// ---------------- routing ----------------
__global__ __launch_bounds__(256) void route_kernel(
    const float* __restrict__ logits,   // [256][16] fp32
    const int* __restrict__ topk_ptr,
    int* __restrict__ counts, int* __restrict__ tokens,
    int* __restrict__ tok_e, int* __restrict__ tok_slot, float* __restrict__ tok_wt)
{
    __shared__ int lds_counts[N_EXP];
    const int t = threadIdx.x;
    if (t < N_EXP) lds_counts[t] = 0;
    __syncthreads();

    int K = topk_ptr[0];
    if (K > 8) K = 8;
    if (K < 1) K = 1;

    float l[N_EXP];
    #pragma unroll
    for (int j = 0; j < N_EXP; ++j) l[j] = logits[t * N_EXP + j];

    float M = l[0];
    #pragma unroll
    for (int j = 1; j < N_EXP; ++j) M = fmaxf(M, l[j]);

    // top-K by logit; strict > keeps lowest index on ties (matches lax.top_k)
    int idx[8]; float lv[8]; unsigned used = 0u;
    for (int k = 0; k < K; ++k) {
        int bi = 0; float bv = -1e30f;
        #pragma unroll
        for (int j = 0; j < N_EXP; ++j)
            if (!((used >> j) & 1u) && l[j] > bv) { bv = l[j]; bi = j; }
        used |= 1u << bi;
        idx[k] = bi; lv[k] = bv;
    }
    float w[8], s = 0.f;
    for (int k = 0; k < K; ++k) { w[k] = __expf(lv[k] - M); s += w[k]; }
    const float inv = 1.0f / s;

    for (int k = 0; k < K; ++k) {
        const int e = idx[k];
        const int slot = atomicAdd(&lds_counts[e], 1);
        tokens[e * MAX_SLOTS + slot] = t;
        tok_e[t * 8 + k] = e; tok_slot[t * 8 + k] = slot; tok_wt[t * 8 + k] = w[k] * inv;
    }
    __syncthreads();
    if (t < N_EXP) counts[t] = lds_counts[t];
}

// ---------------- gather_x: x fp32 -> xe[e][slot][:] bf16 (compact) ----------------
__global__ __launch_bounds__(256) void gather_x_kernel(
    const float* __restrict__ xf, const int* __restrict__ counts,
    const int* __restrict__ tokens, short* __restrict__ xe)
{
    const int e = blockIdx.x, sc = blockIdx.y;     // grid (16,16): 16 slots/block
    const int count = counts[e];
    const int s0 = sc * 16;
    if (s0 >= count) return;
    const int send = (s0 + 16 < count) ? s0 + 16 : count;
    const int cs = threadIdx.x * 8;                // 256 thr x 8 cols = 2048
    for (int s = s0; s < send; ++s) {
        const int tok = tokens[e * MAX_SLOTS + s];
        *(bf16x8*)(xe + ((size_t)e * MAX_SLOTS + s) * H_DIM + cs) =
            pack8(xf + (size_t)tok * H_DIM + cs);
    }
}

// ---------------- GEMM1: act = silu(X_e@Wg^T) * (X_e@Wu^T) ----------------
// grid (16 e, 16 i-blocks of 64). 512 thr = 8 waves: iw=wave&3 (16 i each),
// kh=wave>>2 (k-half of 1024). 32 k-iters of 32. D=4 register pipeline on the
// 2 weight streams (gate,up); A from L2-resident xe. kh=1 publishes partials
// to LDS; kh=0 combines + silu + store (R2-verified epilogue).
template<int MT>
__device__ __forceinline__ void g1_body(
    int ms, int count, const short* __restrict__ xe_e,
    const float* __restrict__ wg, const float* __restrict__ wu,
    int quad, int nl, int lane, int iw, int kh, int i_base, int e,
    short* __restrict__ act, floatx4* red)
{
    const short* ar[MT];
    #pragma unroll
    for (int mt = 0; mt < MT; ++mt) {
        int s = ms + mt * 16 + nl;
        if (s >= count) s = count - 1;     // clamp: padded rows dropped at store
        ar[mt] = xe_e + (size_t)s * H_DIM + kh * (H_DIM / 2) + quad * 8;
    }
    floatx4 ag[MT], au[MT];
    #pragma unroll
    for (int mt = 0; mt < MT; ++mt) { ag[mt] = (floatx4)0.0f; au[mt] = (floatx4)0.0f; }

    // D=4 rotating stages; prologue fills 0..2 with iters 0..2
    float4 sg0[4], sg1[4], su0[4], su1[4];
    #pragma unroll
    for (int d = 0; d < 3; ++d) {
        sg0[d] = *(const float4*)(wg + d * 32);
        sg1[d] = *(const float4*)(wg + d * 32 + 4);
        su0[d] = *(const float4*)(wu + d * 32);
        su1[d] = *(const float4*)(wu + d * 32 + 4);
    }
    for (int j = 0; j < 8; ++j) {          // 32 iters = 8 x 4 (inner static)
        #pragma unroll
        for (int u = 0; u < 4; ++u) {
            const int it = j * 4 + u;
            int pit = it + 3; if (pit > 31) pit = 31;    // clamped prefetch
            const int ps = (u + 3) & 3;                   // literal stage idx
            sg0[ps] = *(const float4*)(wg + pit * 32);
            sg1[ps] = *(const float4*)(wg + pit * 32 + 4);
            su0[ps] = *(const float4*)(wu + pit * 32);
            su1[ps] = *(const float4*)(wu + pit * 32 + 4);
            bf16x8 bg = pack2f4(sg0[u], sg1[u]);
            bf16x8 bu = pack2f4(su0[u], su1[u]);
            #pragma unroll
            for (int mt = 0; mt < MT; ++mt) {
                bf16x8 a = *(const bf16x8*)(ar[mt] + it * 32);
                ag[mt] = __builtin_amdgcn_mfma_f32_16x16x32_bf16(a, bg, ag[mt], 0, 0, 0);
                au[mt] = __builtin_amdgcn_mfma_f32_16x16x32_bf16(a, bu, au[mt], 0, 0, 0);
            }
        }
    }
    // split-K reduce epilogue (R2-verified)
    if (kh) {
        #pragma unroll
        for (int mt = 0; mt < MT; ++mt) {
            red[(((iw * 8 + mt) * 2 + 0) * 64) + lane] = ag[mt];
            red[(((iw * 8 + mt) * 2 + 1) * 64) + lane] = au[mt];
        }
    }
    __syncthreads();
    if (!kh) {
        #pragma unroll
        for (int mt = 0; mt < MT; ++mt) {
            floatx4 g = ag[mt] + red[(((iw * 8 + mt) * 2 + 0) * 64) + lane];
            floatx4 u = au[mt] + red[(((iw * 8 + mt) * 2 + 1) * 64) + lane];
            #pragma unroll
            for (int r = 0; r < 4; ++r) {
                const int slot = ms + mt * 16 + quad * 4 + r;   // D: row=quad*4+r, col=nl
                if (slot < count) {
                    const float gv = g[r], uv = u[r];
                    const float a = gv / (1.0f + __expf(-gv)) * uv;   // silu(g)*u
                    act[(size_t)(e * MAX_SLOTS + slot) * I_DIM + i_base + iw * 16 + nl] = f2bf(a);
                }
            }
        }
    }
    __syncthreads();   // protect LDS reuse on next ms pass
}

__global__ __launch_bounds__(512, 2) void gemm1_kernel(
    const short* __restrict__ xe,     // [16][256][2048] bf16 compact
    const float* __restrict__ w1,     // [16][2048][2048] fp32
    const int* __restrict__ counts,
    short* __restrict__ act)          // [16][256][1024] bf16
{
    __shared__ floatx4 red[4 * 8 * 2 * 64];    // 64 KB (epilogue only)
    const int e = blockIdx.x;
    const int count = counts[e];
    if (count == 0) return;
    const int tid = (int)threadIdx.x;
    const int wave = tid >> 6, lane = tid & 63;
    const int iw = wave & 3, kh = wave >> 2;
    const int nl = lane & 15, quad = lane >> 4;
    const int i_base = blockIdx.y * 64;

    const float* wg = w1 + ((size_t)e * H_DIM + (i_base + iw * 16 + nl)) * H_DIM
                         + kh * (H_DIM / 2) + quad * 8;
    const float* wu = wg + (size_t)I_DIM * H_DIM;    // up rows are +1024 rows
    const short* xe_e = xe + (size_t)e * MAX_SLOTS * H_DIM;

    for (int ms = 0; ms < count; ms += 128) {
        const int rem = count - ms;
        const int nmt = rem >= 128 ? 8 : ((rem + 15) >> 4);   // block-uniform
        switch (nmt) {
            case 1: g1_body<1>(ms, count, xe_e, wg, wu, quad, nl, lane, iw, kh, i_base, e, act, red); break;
            case 2: g1_body<2>(ms, count, xe_e, wg, wu, quad, nl, lane, iw, kh, i_base, e, act, red); break;
            case 3: g1_body<3>(ms, count, xe_e, wg, wu, quad, nl, lane, iw, kh, i_base, e, act, red); break;
            case 4: g1_body<4>(ms, count, xe_e, wg, wu, quad, nl, lane, iw, kh, i_base, e, act, red); break;
            case 5: g1_body<5>(ms, count, xe_e, wg, wu, quad, nl, lane, iw, kh, i_base, e, act, red); break;
            case 6: g1_body<6>(ms, count, xe_e, wg, wu, quad, nl, lane, iw, kh, i_base, e, act, red); break;
            case 7: g1_body<7>(ms, count, xe_e, wg, wu, quad, nl, lane, iw, kh, i_base, e, act, red); break;
            default: g1_body<8>(ms, count, xe_e, wg, wu, quad, nl, lane, iw, kh, i_base, e, act, red); break;
        }
    }
}

// ---------------- GEMM2: y = act_e @ w2[e]^T ----------------
// grid (16 e, 16 h-blocks of 128). 512 thr = 8 waves; wave owns h-rows
// h_base + wave*16 + nl; full K=1024, 32 k-iters of 32. D=8 register
// pipeline on the single weight stream. No LDS, no barriers.
template<int MT>
__device__ __forceinline__ void g2_body(
    int ms, int count, const short* __restrict__ acte,
    const float* __restrict__ wr,
    int quad, int nl, int wave, int h_base, int e,
    short* __restrict__ y)
{
    const short* ar[MT];
    #pragma unroll
    for (int mt = 0; mt < MT; ++mt) {
        int s = ms + mt * 16 + nl;
        if (s >= count) s = count - 1;
        ar[mt] = acte + (size_t)s * I_DIM + quad * 8;
    }
    floatx4 acc[MT];
    #pragma unroll
    for (int mt = 0; mt < MT; ++mt) acc[mt] = (floatx4)0.0f;

    // D=8 rotating stages; prologue fills 0..6 with iters 0..6
    float4 sb0[8], sb1[8];
    #pragma unroll
    for (int d = 0; d < 7; ++d) {
        sb0[d] = *(const float4*)(wr + d * 32);
        sb1[d] = *(const float4*)(wr + d * 32 + 4);
    }
    for (int j = 0; j < 4; ++j) {          // 32 iters = 4 x 8 (inner static)
        #pragma unroll
        for (int u = 0; u < 8; ++u) {
            const int it = j * 8 + u;
            int pit = it + 7; if (pit > 31) pit = 31;
            const int ps = (u + 7) & 7;                   // literal stage idx
            sb0[ps] = *(const float4*)(wr + pit * 32);
            sb1[ps] = *(const float4*)(wr + pit * 32 + 4);
            bf16x8 b = pack2f4(sb0[u], sb1[u]);
            #pragma unroll
            for (int mt = 0; mt < MT; ++mt) {
                bf16x8 a = *(const bf16x8*)(ar[mt] + it * 32);
                acc[mt] = __builtin_amdgcn_mfma_f32_16x16x32_bf16(a, b, acc[mt], 0, 0, 0);
            }
        }
    }
    #pragma unroll
    for (int mt = 0; mt < MT; ++mt) {
        #pragma unroll
        for (int r = 0; r < 4; ++r) {
            const int slot = ms + mt * 16 + quad * 4 + r;
            if (slot < count)
                y[(size_t)(e * MAX_SLOTS + slot) * H_DIM + h_base + wave * 16 + nl] = f2bf(acc[mt][r]);
        }
    }
}

__global__ __launch_bounds__(512, 2) void gemm2_kernel(
    const short* __restrict__ act,    // [16][256][1024] bf16
    const float* __restrict__ w2,     // [16][2048][1024] fp32
    const int* __restrict__ counts,
    short* __restrict__ y)            // [16][256][2048] bf16
{
    const int e = blockIdx.x;
    const int count = counts[e];
    if (count == 0) return;
    const int tid = (int)threadIdx.x;
    const int wave = tid >> 6, lane = tid & 63;
    const int nl = lane & 15, quad = lane >> 4;
    const int h_base = blockIdx.y * 128;

    const float* wr = w2 + ((size_t)e * H_DIM + h_base + wave * 16 + nl) * I_DIM + quad * 8;
    const short* acte = act + (size_t)e * MAX_SLOTS * I_DIM;

    for (int ms = 0; ms < count; ms += 128) {
        const int rem = count - ms;
        const int nmt = rem >= 128 ? 8 : ((rem + 15) >> 4);
        switch (nmt) {
            case 1: g2_body<1>(ms, count, acte, wr, quad, nl, wave, h_base, e, y); break;
            case 2: g2_body<2>(ms, count, acte, wr, quad, nl, wave, h_base, e, y); break;
            case 3: g2_body<3>(ms, count, acte, wr, quad, nl, wave, h_base, e, y); break;
            case 4: g2_body<4>(ms, count, acte, wr, quad, nl, wave, h_base, e, y); break;
            case 5: g2_body<5>(ms, count, acte, wr, quad, nl, wave, h_base, e, y); break;
            case 6: g2_body<6>(ms, count, acte, wr, quad, nl, wave, h_base, e, y); break;
            case 7: g2_body<7>(ms, count, acte, wr, quad, nl, wave, h_base, e, y); break;
            default: g2_body<8>(ms, count, acte, wr, quad, nl, wave, h_base, e, y); break;
        }
    }
}

// ---------------- gather: out[t][h] = sum_k wt * y[e_k][slot_k][h] (fp32) ----------------
__global__ __launch_bounds__(256) void gather_kernel(
    const short* __restrict__ y, const int* __restrict__ topk_ptr,
    const int* __restrict__ tok_e, const int* __restrict__ tok_slot,
    const float* __restrict__ tok_wt, float* __restrict__ out)
{
    const int t = blockIdx.x;
    int K = topk_ptr[0];
    if (K > 8) K = 8;
    if (K < 1) K = 1;
    int e[8], sl[8]; float w[8];
    for (int k = 0; k < K; ++k) {
        e[k] = tok_e[t * 8 + k]; sl[k] = tok_slot[t * 8 + k]; w[k] = tok_wt[t * 8 + k];
    }
    for (int h = threadIdx.x; h < H_DIM; h += 256) {
        float s = 0.f;
        for (int k = 0; k < K; ++k)
            s += w[k] * bf2f(y[(size_t)(e[k] * MAX_SLOTS + sl[k]) * H_DIM + h]);
        out[(size_t)t * H_DIM + h] = s;
    }
}

// ---------------- launch ----------------
extern "C" void kernel_launch(void* const* d_in, const int* in_sizes, int n_in,
                              void* d_out, int out_size, void* d_ws, size_t ws_size,
                              hipStream_t stream)
{
    const float* x  = (const float*)d_in[0];
    const float* rl = (const float*)d_in[1];
    const float* w1 = (const float*)d_in[2];
    const float* w2 = (const float*)d_in[3];
    const int* topk = (const int*)d_in[4];

    char* ws = (char*)d_ws;
    int*   counts   = (int*)  (ws + 0);          //   64 B
    int*   tokens   = (int*)  (ws + 256);        //  16 KB [16][256]
    int*   tok_e    = (int*)  (ws + 16640);      //   8 KB [256][8]
    int*   tok_slot = (int*)  (ws + 24832);      //   8 KB
    float* tok_wt   = (float*)(ws + 33024);      //   8 KB
    short* act      = (short*)(ws + 1114112);    //   8 MB [16][256][1024] bf16
    short* yb       = (short*)(ws + 9502720);    //  16 MB [16][256][2048] bf16
    short* xe       = (short*)(ws + 26279936);   //  16 MB [16][256][2048] bf16

    route_kernel<<<1, 256, 0, stream>>>(rl, topk, counts, tokens, tok_e, tok_slot, tok_wt);
    gather_x_kernel<<<dim3(N_EXP, 16), 256, 0, stream>>>(x, counts, tokens, xe);
    gemm1_kernel<<<dim3(N_EXP, 16), 512, 0, stream>>>(xe, w1, counts, act);
    gemm2_kernel<<<dim3(N_EXP, 16), 512, 0, stream>>>(act, w2, counts, yb);
    gather_kernel<<<T_TOK, 256, 0, stream>>>(yb, topk, tok_e, tok_slot, tok_wt, (float*)d_out);
}